// Round 7
// baseline (418.644 us; speedup 1.0000x reference)
//
#include <hip/hip_runtime.h>
#include <cmath>

// Problem constants (from reference)
#define NB 4
#define NP 8192            // 2^13 points per batch
#define NE 262144          // 2^18 edges per batch
#define NCIN 32
#define NCOUT 32
#define NH 16
#define GAMMA 4.0f
#define NFEAT (NB * NP * NCIN)      // 1,048,576 floats (4 MB)
#define NOUT  (NB * NP * NCOUT)     // 1,048,576 floats (4 MB)
#define TILES_PER_BATCH (NE / 64)
#define NXCD 8
#define SLICE (NP * NCOUT)          // 262,144 floats = 1 MB: one batch's out rows
#define QCAP 8192                   // 16-edge chunks per queue (2 queues/batch)

typedef _Float16 half8 __attribute__((ext_vector_type(8)));
typedef float floatx4 __attribute__((ext_vector_type(4)));

// ---------------------------------------------------------------------------
// Prep: zero partial slices (8 MB) + overflow (4 MB) + queue counters, and
// build the f16 feature table. All streaming, ~4 us.
// ws layout: partial[8][1MB] | ovf[4MB] | f16[2MB] | qcnt[8*16 ints]
// ---------------------------------------------------------------------------
__global__ __launch_bounds__(256)
void prep_kernel(const float* __restrict__ features,
                 _Float16* __restrict__ f16t,
                 floatx4* __restrict__ zero4,     // partial+ovf = 786432 float4
                 int* __restrict__ qcnt)
{
    const int i = blockIdx.x * blockDim.x + threadIdx.x;    // 0 .. 262143
    const floatx4 z = {0.f, 0.f, 0.f, 0.f};
    #pragma unroll
    for (int k = 0; k < 3; ++k)
        zero4[(long)k * 262144 + i] = z;

    if (i < 128) qcnt[i] = 0;

    if (i < NFEAT / 8) {                        // f32 -> f16 table
        const floatx4* src = (const floatx4*)features + (long)i * 2;
        floatx4 v0 = src[0], v1 = src[1];
        half8 h;
        h[0] = (_Float16)v0[0]; h[1] = (_Float16)v0[1];
        h[2] = (_Float16)v0[2]; h[3] = (_Float16)v0[3];
        h[4] = (_Float16)v1[0]; h[5] = (_Float16)v1[1];
        h[6] = (_Float16)v1[2]; h[7] = (_Float16)v1[3];
        *((half8*)f16t + i) = h;
    }
}

// cvt-only variant for the fallback path.
__global__ __launch_bounds__(256)
void cvt_f16_kernel(const float* __restrict__ features, _Float16* __restrict__ f16t)
{
    const int i = blockIdx.x * blockDim.x + threadIdx.x;    // 0 .. 131071
    const floatx4* src = (const floatx4*)features + (long)i * 2;
    floatx4 v0 = src[0], v1 = src[1];
    half8 h;
    h[0] = (_Float16)v0[0]; h[1] = (_Float16)v0[1];
    h[2] = (_Float16)v0[2]; h[3] = (_Float16)v0[3];
    h[4] = (_Float16)v1[0]; h[5] = (_Float16)v1[1];
    h[6] = (_Float16)v1[2]; h[7] = (_Float16)v1[3];
    *((half8*)f16t + i) = h;
}

// ---------------------------------------------------------------------------
// Reduce: out = scale * (slice[2b] + slice[2b+1] + ovf).  16 MB streaming.
// Batch b's rows live in partial slices 2b and 2b+1 (its two home XCDs) plus
// the device-scope overflow buffer (steal path, normally all-zero).
// ---------------------------------------------------------------------------
__global__ __launch_bounds__(256)
void reduce_kernel(const floatx4* __restrict__ partial4,   // 8 slices
                   const floatx4* __restrict__ ovf4,       // out-shaped
                   const int* __restrict__ n_norm_p,
                   floatx4* __restrict__ out4)
{
    const int i = blockIdx.x * blockDim.x + threadIdx.x;    // 0 .. 262143
    const int nn = n_norm_p[0];
    const float scale = (nn > 0) ? rsqrtf((float)nn) : 1.0f;
    const int b = i >> 16;                                   // 65536 float4/batch
    const int li = i & 65535;                                // idx within slice
    floatx4 s = partial4[(long)(2 * b) * 65536 + li]
              + partial4[(long)(2 * b + 1) * 65536 + li]
              + ovf4[i];
    out4[i] = s * scale;
}

// ---------------------------------------------------------------------------
// Main kernel: per-XCD WORK QUEUES keyed on hardware XCC_ID.
//
// Rounds 3-6 assumed bid&7 == physical XCD; round 6's null result (identical
// FETCH/WRITE with XCD-private partials) says that heuristic likely never
// held, so every XCD's hot set was 4 batches of features + 4 MB partial ->
// L2 thrash. Here affinity is guaranteed by hardware: queue x holds only
// batch (x>>1)'s chunks, and blocks pop from the queue of the XCD they are
// PHYSICALLY running on (s_getreg XCC_ID, HW-verified m09). Hot set per XCD:
// 512 KB f16 features + 1 MB private slice -> L2-resident.
//
// Stealing (only if some XCD gets no/few blocks): device-scope atomics into
// a separate overflow buffer -- never mixes scopes on the same lines.
//
// GEMM view: msg[e, o] = sum_k Z[e,k] * W2T[k,o],  k = h*32 + i, K = 512
//   Z[e, h*32+i] = rbf_h(e) * x_src[e][i]
// MFMA f32_16x16x32_f16 layouts (HW-verified, learn_hip m89/m91):
//   A: lane holds A[m=lane&15][k_local=(lane>>4)*8+j], j=0..7
//   B: lane holds B[k_local][n=lane&15]
//   D: lane holds D[row=(lane>>4)*4+rr][col=m]
// ---------------------------------------------------------------------------
__global__ __launch_bounds__(256, 4)
void pconv_queue_kernel(const _Float16* __restrict__ feat16,
                        const float* __restrict__ edge_vec,
                        const float* __restrict__ W,
                        const float* __restrict__ mu,
                        const int* __restrict__ edge_src,
                        const int* __restrict__ edge_dst,
                        float* __restrict__ partial,   // 8 x 1 MB slices
                        float* __restrict__ ovf,       // out-shaped, 4 MB
                        int* __restrict__ qcnt)        // 8 counters, 64B apart
{
    __shared__ _Float16 wsw[16 * 2 * 64 * 8];   // 32 KiB, B-fragment order
    __shared__ float mus[16];

    const int tid = threadIdx.x;
    for (int idx = tid; idx < 16384; idx += 256) {
        int j = idx & 7;
        int l = (idx >> 3) & 63;
        int u = (idx >> 9) & 1;
        int s = idx >> 10;
        int n = (l & 15) + (u << 4);          // output channel o
        int i = ((l >> 4) << 3) | j;          // input channel
        wsw[idx] = (_Float16)W[(s * NCOUT + n) * NCIN + i];
    }
    if (tid < 16) mus[tid] = mu[tid];
    __syncthreads();

    unsigned xcc;
    asm volatile("s_getreg_b32 %0, hwreg(HW_REG_XCC_ID)" : "=s"(xcc));
    xcc &= 7;
    const int myb = (int)(xcc >> 1);

    const int lane = tid & 63;
    const int m    = lane & 15;   // A-row (edge); D-col (channel) in epilogue
    const int q    = lane >> 4;

    for (int attempt = 0; attempt < 8; ++attempt) {
        const int qi = (int)((xcc + attempt) & 7);
        const int qb = qi >> 1;                       // batch served by queue qi
        const bool local = (qb == myb);               // wave-uniform

        const _Float16* fbase = feat16 + (long)qb * NP * NCIN;
        float* obase = local ? (partial + (long)xcc * SLICE)
                             : (ovf + (long)qb * SLICE);
        const long ebq = (long)qb * NE + (long)(qi & 1) * (QCAP * 16);

        while (true) {
            int c = 0;
            if (lane == 0) c = atomicAdd(qcnt + qi * 16, 1);
            c = __shfl(c, 0);                         // broadcast pop to wave
            if (c >= QCAP) break;

            const long e0 = ebq + (long)c * 16;       // this wave's 16 edges
            const long ge = e0 + m;
            const int  src = __builtin_nontemporal_load(edge_src + ge);

            // gather: one 64 B line per edge, L2-resident table
            half8 xh = *(const half8*)(fbase + (long)src * NCIN + q * 8);

            const float* ev = edge_vec + ge * 3;
            float vx = __builtin_nontemporal_load(ev + 0);
            float vy = __builtin_nontemporal_load(ev + 1);
            float vz = __builtin_nontemporal_load(ev + 2);
            // self-interaction zeroing in ref is a numeric no-op (r<1e-10 -> r=0)
            float r = sqrtf(vx * vx + vy * vy + vz * vz);

            float rbf[16];
            #pragma unroll
            for (int s = 0; s < 16; ++s) {
                float d = r - mus[s];
                rbf[s] = __expf(-GAMMA * d * d);
            }

            floatx4 accLo = {0.f, 0.f, 0.f, 0.f};   // channels 0..15
            floatx4 accHi = {0.f, 0.f, 0.f, 0.f};   // channels 16..31

            #pragma unroll
            for (int s = 0; s < 16; ++s) {
                const _Float16 rh = (_Float16)rbf[s];
                half8 a = xh * rh;                   // 4x v_pk_mul_f16
                half8 b0 = *(const half8*)(wsw + ((s * 2 + 0) * 64 + lane) * 8);
                half8 b1 = *(const half8*)(wsw + ((s * 2 + 1) * 64 + lane) * 8);
                accLo = __builtin_amdgcn_mfma_f32_16x16x32_f16(a, b0, accLo, 0, 0, 0);
                accHi = __builtin_amdgcn_mfma_f32_16x16x32_f16(a, b1, accHi, 0, 0, 0);
            }

            // Epilogue: lane holds D[row=q*4+rr][col=m]. 16 lanes cover 16
            // consecutive channels -> coalesced 64 B atomic segments.
            if (local) {
                #pragma unroll
                for (int rr = 0; rr < 4; ++rr) {
                    const long e2  = e0 + q * 4 + rr;
                    const int  dst = __builtin_nontemporal_load(edge_dst + e2);
                    float* orow = obase + (long)dst * NCOUT;
                    __hip_atomic_fetch_add(orow + m,      accLo[rr],
                        __ATOMIC_RELAXED, __HIP_MEMORY_SCOPE_WORKGROUP);
                    __hip_atomic_fetch_add(orow + m + 16, accHi[rr],
                        __ATOMIC_RELAXED, __HIP_MEMORY_SCOPE_WORKGROUP);
                }
            } else {
                #pragma unroll
                for (int rr = 0; rr < 4; ++rr) {
                    const long e2  = e0 + q * 4 + rr;
                    const int  dst = __builtin_nontemporal_load(edge_dst + e2);
                    float* orow = obase + (long)dst * NCOUT;
                    atomicAdd(orow + m,      accLo[rr]);
                    atomicAdd(orow + m + 16, accHi[rr]);
                }
            }
        }
    }
}

// ---------------------------------------------------------------------------
// Fallback A (ws >= 2 MB): round-5 kernel verbatim (best measured: 248 us).
// ---------------------------------------------------------------------------
__global__ __launch_bounds__(256, 4)
void pconv_f16_kernel(const _Float16* __restrict__ feat16,
                      const float* __restrict__ edge_vec,
                      const float* __restrict__ W,
                      const float* __restrict__ mu,
                      const int* __restrict__ edge_src,
                      const int* __restrict__ edge_dst,
                      const int* __restrict__ n_norm_p,
                      float* __restrict__ out)
{
    __shared__ _Float16 wsw[16 * 2 * 64 * 8];
    __shared__ float mus[16];

    const int tid = threadIdx.x;
    for (int idx = tid; idx < 16384; idx += 256) {
        int j = idx & 7;
        int l = (idx >> 3) & 63;
        int u = (idx >> 9) & 1;
        int s = idx >> 10;
        int n = (l & 15) + (u << 4);
        int i = ((l >> 4) << 3) | j;
        wsw[idx] = (_Float16)W[(s * NCOUT + n) * NCIN + i];
    }
    if (tid < 16) mus[tid] = mu[tid];
    __syncthreads();

    const int lane = tid & 63;
    const int wv   = tid >> 6;
    const int m    = lane & 15;
    const int q    = lane >> 4;

    const int nn = n_norm_p[0];
    const float scale = (nn > 0) ? rsqrtf((float)nn) : 1.0f;

    const int g    = blockIdx.x & 7;
    const int bb   = g >> 1;
    const int sub  = g & 1;
    const int bi   = blockIdx.x >> 3;

    const _Float16* fbase = feat16 + ((long)bb << 13) * NCIN;
    float* obase = out + ((long)bb << 13) * NCOUT;
    const long ebatch = (long)bb * NE;

    for (int i = bi; i < TILES_PER_BATCH / 2; i += 128) {
        const int  tloc  = (i << 1) + sub;
        const long ebase = ebatch + (long)tloc * 64 + (long)wv * 16;
        const long ge    = ebase + m;
        const int  src   = __builtin_nontemporal_load(edge_src + ge);

        half8 xh = *(const half8*)(fbase + (long)src * NCIN + q * 8);

        const float* ev = edge_vec + ge * 3;
        float vx = __builtin_nontemporal_load(ev + 0);
        float vy = __builtin_nontemporal_load(ev + 1);
        float vz = __builtin_nontemporal_load(ev + 2);
        float r = sqrtf(vx * vx + vy * vy + vz * vz);

        float rbf[16];
        #pragma unroll
        for (int s = 0; s < 16; ++s) {
            float d = r - mus[s];
            rbf[s] = __expf(-GAMMA * d * d);
        }

        floatx4 accLo = {0.f, 0.f, 0.f, 0.f};
        floatx4 accHi = {0.f, 0.f, 0.f, 0.f};

        #pragma unroll
        for (int s = 0; s < 16; ++s) {
            const _Float16 rh = (_Float16)rbf[s];
            half8 a = xh * rh;
            half8 b0 = *(const half8*)(wsw + ((s * 2 + 0) * 64 + lane) * 8);
            half8 b1 = *(const half8*)(wsw + ((s * 2 + 1) * 64 + lane) * 8);
            accLo = __builtin_amdgcn_mfma_f32_16x16x32_f16(a, b0, accLo, 0, 0, 0);
            accHi = __builtin_amdgcn_mfma_f32_16x16x32_f16(a, b1, accHi, 0, 0, 0);
        }

        #pragma unroll
        for (int rr = 0; rr < 4; ++rr) {
            const long e2  = ebase + q * 4 + rr;
            const int  dst = __builtin_nontemporal_load(edge_dst + e2);
            float* orow = obase + (long)dst * NCOUT;
            atomicAdd(orow + m,      accLo[rr] * scale);
            atomicAdd(orow + m + 16, accHi[rr] * scale);
        }
    }
}

// ---------------------------------------------------------------------------
// Fallback B (no workspace): round-3 kernel (f32 gathers).
// ---------------------------------------------------------------------------
__global__ __launch_bounds__(256, 4)
void pconv_mfma_kernel(const float* __restrict__ features,
                       const float* __restrict__ edge_vec,
                       const float* __restrict__ W,
                       const float* __restrict__ mu,
                       const int* __restrict__ edge_src,
                       const int* __restrict__ edge_dst,
                       const int* __restrict__ n_norm_p,
                       float* __restrict__ out)
{
    __shared__ _Float16 wsw[16 * 2 * 64 * 8];
    __shared__ float mus[16];

    const int tid = threadIdx.x;
    for (int idx = tid; idx < 16384; idx += 256) {
        int j = idx & 7;
        int l = (idx >> 3) & 63;
        int u = (idx >> 9) & 1;
        int s = idx >> 10;
        int n = (l & 15) + (u << 4);
        int i = ((l >> 4) << 3) | j;
        wsw[idx] = (_Float16)W[(s * NCOUT + n) * NCIN + i];
    }
    if (tid < 16) mus[tid] = mu[tid];
    __syncthreads();

    const int lane = tid & 63;
    const int wv   = tid >> 6;
    const int m    = lane & 15;
    const int q    = lane >> 4;

    const int nn = n_norm_p[0];
    const float scale = (nn > 0) ? rsqrtf((float)nn) : 1.0f;

    const int g    = blockIdx.x & 7;
    const int bb   = g >> 1;
    const int sub  = g & 1;
    const int bi   = blockIdx.x >> 3;

    const float* fbase = features + ((long)bb << 13) * NCIN;
    float* obase = out + ((long)bb << 13) * NCOUT;
    const long ebatch = (long)bb * NE;

    for (int i = bi; i < TILES_PER_BATCH / 2; i += 128) {
        const int  tloc  = (i << 1) + sub;
        const long ebase = ebatch + (long)tloc * 64 + (long)wv * 16;
        const long ge    = ebase + m;
        const int  src   = edge_src[ge];

        const float* xrow = fbase + (long)src * NCIN + q * 8;
        floatx4 xa = *(const floatx4*)(xrow);
        floatx4 xb = *(const floatx4*)(xrow + 4);

        const float* ev = edge_vec + ge * 3;
        float vx = ev[0], vy = ev[1], vz = ev[2];
        float r = sqrtf(vx * vx + vy * vy + vz * vz);

        float rbf[16];
        #pragma unroll
        for (int s = 0; s < 16; ++s) {
            float d = r - mus[s];
            rbf[s] = __expf(-GAMMA * d * d);
        }

        floatx4 accLo = {0.f, 0.f, 0.f, 0.f};
        floatx4 accHi = {0.f, 0.f, 0.f, 0.f};

        #pragma unroll
        for (int s = 0; s < 16; ++s) {
            const float rb = rbf[s];
            half8 a;
            a[0] = (_Float16)(rb * xa[0]);
            a[1] = (_Float16)(rb * xa[1]);
            a[2] = (_Float16)(rb * xa[2]);
            a[3] = (_Float16)(rb * xa[3]);
            a[4] = (_Float16)(rb * xb[0]);
            a[5] = (_Float16)(rb * xb[1]);
            a[6] = (_Float16)(rb * xb[2]);
            a[7] = (_Float16)(rb * xb[3]);
            half8 b0 = *(const half8*)(wsw + ((s * 2 + 0) * 64 + lane) * 8);
            half8 b1 = *(const half8*)(wsw + ((s * 2 + 1) * 64 + lane) * 8);
            accLo = __builtin_amdgcn_mfma_f32_16x16x32_f16(a, b0, accLo, 0, 0, 0);
            accHi = __builtin_amdgcn_mfma_f32_16x16x32_f16(a, b1, accHi, 0, 0, 0);
        }

        #pragma unroll
        for (int rr = 0; rr < 4; ++rr) {
            const long e2  = ebase + q * 4 + rr;
            const int  dst = edge_dst[e2];
            float* orow = obase + (long)dst * NCOUT;
            atomicAdd(orow + m,      accLo[rr] * scale);
            atomicAdd(orow + m + 16, accHi[rr] * scale);
        }
    }
}

extern "C" void kernel_launch(void* const* d_in, const int* in_sizes, int n_in,
                              void* d_out, int out_size, void* d_ws, size_t ws_size,
                              hipStream_t stream) {
    const float* features = (const float*)d_in[0];
    const float* edge_vec = (const float*)d_in[1];
    const float* W        = (const float*)d_in[2];
    const float* mu       = (const float*)d_in[3];
    const int*   edge_src = (const int*)d_in[4];
    const int*   edge_dst = (const int*)d_in[5];
    const int*   n_norm   = (const int*)d_in[6];
    float* out = (float*)d_out;

    // ws layout: partial[8][1MB] | ovf[4MB] | f16[2MB] | qcnt[4KB]
    const size_t part_bytes = (size_t)NXCD * SLICE * sizeof(float);  //  8 MB
    const size_t ovf_bytes  = (size_t)NOUT * sizeof(float);          //  4 MB
    const size_t f16_bytes  = (size_t)NFEAT * sizeof(_Float16);      //  2 MB
    const size_t q_bytes    = 4096;
    const size_t need_full  = part_bytes + ovf_bytes + f16_bytes + q_bytes;

    if (d_ws != nullptr && ws_size >= need_full) {
        char* ws = (char*)d_ws;
        float*    partial = (float*)ws;
        float*    ovf     = (float*)(ws + part_bytes);
        _Float16* f16t    = (_Float16*)(ws + part_bytes + ovf_bytes);
        int*      qcnt    = (int*)(ws + part_bytes + ovf_bytes + f16_bytes);

        prep_kernel<<<1024, 256, 0, stream>>>(features, f16t,
                                              (floatx4*)partial, qcnt);
        pconv_queue_kernel<<<1024, 256, 0, stream>>>(f16t, edge_vec, W, mu,
                                                     edge_src, edge_dst,
                                                     partial, ovf, qcnt);
        reduce_kernel<<<1024, 256, 0, stream>>>((const floatx4*)partial,
                                                (const floatx4*)ovf,
                                                n_norm, (floatx4*)out);
    } else if (d_ws != nullptr && ws_size >= f16_bytes) {
        hipMemsetAsync(out, 0, (size_t)out_size * sizeof(float), stream);
        _Float16* f16t = (_Float16*)d_ws;
        cvt_f16_kernel<<<NFEAT / 8 / 256, 256, 0, stream>>>(features, f16t);
        pconv_f16_kernel<<<1024, 256, 0, stream>>>(f16t, edge_vec, W, mu,
                                                   edge_src, edge_dst, n_norm, out);
    } else {
        hipMemsetAsync(out, 0, (size_t)out_size * sizeof(float), stream);
        pconv_mfma_kernel<<<1024, 256, 0, stream>>>(features, edge_vec, W, mu,
                                                    edge_src, edge_dst, n_norm, out);
    }
}

// Round 8
// 297.425 us; speedup vs baseline: 1.4076x; 1.4076x over previous
//
#include <hip/hip_runtime.h>
#include <cmath>

// Problem constants (from reference)
#define NB 4
#define NP 8192            // 2^13 points per batch
#define NE 262144          // 2^18 edges per batch
#define NCIN 32
#define NCOUT 32
#define NH 16
#define GAMMA 4.0f
#define NFEAT (NB * NP * NCIN)      // 1,048,576 floats (4 MB)
#define NOUT  (NB * NP * NCOUT)     // 1,048,576 floats (4 MB)
#define TILES_PER_BATCH (NE / 64)
#define NXCD 8
#define SLICE (NP * NCOUT)          // 262,144 floats = 1 MB: one batch's out rows
#define QCAP 8192                   // 16-edge chunks per queue (2 queues/batch)
#define SUPER 64                    // chunks per pop: 64 chunks = 1024 edges
#define NSUPER (QCAP / SUPER)       // 128 super-chunks per queue

typedef _Float16 half8 __attribute__((ext_vector_type(8)));
typedef float floatx4 __attribute__((ext_vector_type(4)));

// ---------------------------------------------------------------------------
// Prep: zero partial slices (8 MB) + overflow (4 MB) + queue counters, and
// build the f16 feature table. All streaming, ~4 us.
// ws layout: partial[8][1MB] | ovf[4MB] | f16[2MB] | qcnt[8*16 ints]
// ---------------------------------------------------------------------------
__global__ __launch_bounds__(256)
void prep_kernel(const float* __restrict__ features,
                 _Float16* __restrict__ f16t,
                 floatx4* __restrict__ zero4,     // partial+ovf = 786432 float4
                 int* __restrict__ qcnt)
{
    const int i = blockIdx.x * blockDim.x + threadIdx.x;    // 0 .. 262143
    const floatx4 z = {0.f, 0.f, 0.f, 0.f};
    #pragma unroll
    for (int k = 0; k < 3; ++k)
        zero4[(long)k * 262144 + i] = z;

    if (i < 128) qcnt[i] = 0;

    if (i < NFEAT / 8) {                        // f32 -> f16 table
        const floatx4* src = (const floatx4*)features + (long)i * 2;
        floatx4 v0 = src[0], v1 = src[1];
        half8 h;
        h[0] = (_Float16)v0[0]; h[1] = (_Float16)v0[1];
        h[2] = (_Float16)v0[2]; h[3] = (_Float16)v0[3];
        h[4] = (_Float16)v1[0]; h[5] = (_Float16)v1[1];
        h[6] = (_Float16)v1[2]; h[7] = (_Float16)v1[3];
        *((half8*)f16t + i) = h;
    }
}

// cvt-only variant for the fallback path.
__global__ __launch_bounds__(256)
void cvt_f16_kernel(const float* __restrict__ features, _Float16* __restrict__ f16t)
{
    const int i = blockIdx.x * blockDim.x + threadIdx.x;    // 0 .. 131071
    const floatx4* src = (const floatx4*)features + (long)i * 2;
    floatx4 v0 = src[0], v1 = src[1];
    half8 h;
    h[0] = (_Float16)v0[0]; h[1] = (_Float16)v0[1];
    h[2] = (_Float16)v0[2]; h[3] = (_Float16)v0[3];
    h[4] = (_Float16)v1[0]; h[5] = (_Float16)v1[1];
    h[6] = (_Float16)v1[2]; h[7] = (_Float16)v1[3];
    *((half8*)f16t + i) = h;
}

// ---------------------------------------------------------------------------
// Reduce: out = scale * (slice[2b] + slice[2b+1] + ovf).  16 MB streaming.
// ---------------------------------------------------------------------------
__global__ __launch_bounds__(256)
void reduce_kernel(const floatx4* __restrict__ partial4,   // 8 slices
                   const floatx4* __restrict__ ovf4,       // out-shaped
                   const int* __restrict__ n_norm_p,
                   floatx4* __restrict__ out4)
{
    const int i = blockIdx.x * blockDim.x + threadIdx.x;    // 0 .. 262143
    const int nn = n_norm_p[0];
    const float scale = (nn > 0) ? rsqrtf((float)nn) : 1.0f;
    const int b = i >> 16;                                   // 65536 float4/batch
    const int li = i & 65535;                                // idx within slice
    floatx4 s = partial4[(long)(2 * b) * 65536 + li]
              + partial4[(long)(2 * b + 1) * 65536 + li]
              + ovf4[i];
    out4[i] = s * scale;
}

// ---------------------------------------------------------------------------
// Main kernel: per-XCD work queues keyed on hardware XCC_ID (round-7
// structure, PROVEN: FETCH 440 MB -> 13 MB), with COARSE BLOCK-LEVEL pops.
//
// Round-7 post-mortem: 65536 per-wave pops / 8 counters = 8192 serialized
// same-address device-scope RMWs per counter x ~41 ns = the entire 337 us.
// Fix: one pop per BLOCK per super-chunk of 1024 edges (LDS broadcast);
// pops per counter drop to ~128 (+~128 empty steal probes) ~= 6 us.
//
// Queue x holds only batch (x>>1)'s chunks; blocks pop the queue of the XCD
// they PHYSICALLY run on (s_getreg XCC_ID, HW-verified m09). Hot set per
// XCD: 512 KB f16 features + 1 MB private partial slice -> L2-resident.
// Local scatter: workgroup-scope (L2-executed) atomics into this XCD's
// private slice. Steal path (only if an XCD is starved of blocks):
// device-scope atomics into a separate overflow buffer - scopes never mix
// on the same lines.
//
// GEMM view: msg[e, o] = sum_k Z[e,k] * W2T[k,o],  k = h*32 + i, K = 512
//   Z[e, h*32+i] = rbf_h(e) * x_src[e][i]
// MFMA f32_16x16x32_f16 layouts (HW-verified, learn_hip m89/m91):
//   A: lane holds A[m=lane&15][k_local=(lane>>4)*8+j], j=0..7
//   B: lane holds B[k_local][n=lane&15]
//   D: lane holds D[row=(lane>>4)*4+rr][col=m]
// ---------------------------------------------------------------------------
__global__ __launch_bounds__(256, 4)
void pconv_queue_kernel(const _Float16* __restrict__ feat16,
                        const float* __restrict__ edge_vec,
                        const float* __restrict__ W,
                        const float* __restrict__ mu,
                        const int* __restrict__ edge_src,
                        const int* __restrict__ edge_dst,
                        float* __restrict__ partial,   // 8 x 1 MB slices
                        float* __restrict__ ovf,       // out-shaped, 4 MB
                        int* __restrict__ qcnt)        // 8 counters, 64B apart
{
    __shared__ _Float16 wsw[16 * 2 * 64 * 8];   // 32 KiB, B-fragment order
    __shared__ float mus[16];
    __shared__ int sc_sh;

    const int tid = threadIdx.x;
    for (int idx = tid; idx < 16384; idx += 256) {
        int j = idx & 7;
        int l = (idx >> 3) & 63;
        int u = (idx >> 9) & 1;
        int s = idx >> 10;
        int n = (l & 15) + (u << 4);          // output channel o
        int i = ((l >> 4) << 3) | j;          // input channel
        wsw[idx] = (_Float16)W[(s * NCOUT + n) * NCIN + i];
    }
    if (tid < 16) mus[tid] = mu[tid];
    __syncthreads();

    unsigned xcc;
    asm volatile("s_getreg_b32 %0, hwreg(HW_REG_XCC_ID)" : "=s"(xcc));
    xcc &= 7;
    const int myb = (int)(xcc >> 1);

    const int lane = tid & 63;
    const int wv   = tid >> 6;
    const int m    = lane & 15;   // A-row (edge); D-col (channel) in epilogue
    const int q    = lane >> 4;

    for (int attempt = 0; attempt < 8; ++attempt) {
        const int qi = (int)((xcc + attempt) & 7);
        const int qb = qi >> 1;                       // batch served by queue qi
        const bool local = (qb == myb);               // block-uniform

        const _Float16* fbase = feat16 + (long)qb * NP * NCIN;
        float* obase = local ? (partial + (long)xcc * SLICE)
                             : (ovf + (long)qb * SLICE);
        const long ebq = (long)qb * NE + (long)(qi & 1) * (QCAP * 16);

        while (true) {
            // ---- block-level pop: ONE device-scope atomic per 1024 edges
            if (tid == 0) sc_sh = atomicAdd(qcnt + qi * 16, 1);
            __syncthreads();
            const int sc = sc_sh;
            __syncthreads();                          // protect sc_sh reuse
            if (sc >= NSUPER) break;                  // block-uniform

            #pragma unroll 1
            for (int it = 0; it < SUPER / 4; ++it) {  // 16 iters per wave
                const int  c  = sc * SUPER + wv * (SUPER / 4) + it;
                const long e0 = ebq + (long)c * 16;   // this wave's 16 edges
                const long ge = e0 + m;
                const int  src = __builtin_nontemporal_load(edge_src + ge);

                // gather: one 64 B line per edge, L2-resident table
                half8 xh = *(const half8*)(fbase + (long)src * NCIN + q * 8);

                const float* ev = edge_vec + ge * 3;
                float vx = __builtin_nontemporal_load(ev + 0);
                float vy = __builtin_nontemporal_load(ev + 1);
                float vz = __builtin_nontemporal_load(ev + 2);
                // self-interaction zeroing in ref is a numeric no-op
                float r = sqrtf(vx * vx + vy * vy + vz * vz);

                float rbf[16];
                #pragma unroll
                for (int s = 0; s < 16; ++s) {
                    float d = r - mus[s];
                    rbf[s] = __expf(-GAMMA * d * d);
                }

                floatx4 accLo = {0.f, 0.f, 0.f, 0.f};   // channels 0..15
                floatx4 accHi = {0.f, 0.f, 0.f, 0.f};   // channels 16..31

                #pragma unroll
                for (int s = 0; s < 16; ++s) {
                    const _Float16 rh = (_Float16)rbf[s];
                    half8 a = xh * rh;                   // 4x v_pk_mul_f16
                    half8 b0 = *(const half8*)(wsw + ((s * 2 + 0) * 64 + lane) * 8);
                    half8 b1 = *(const half8*)(wsw + ((s * 2 + 1) * 64 + lane) * 8);
                    accLo = __builtin_amdgcn_mfma_f32_16x16x32_f16(a, b0, accLo, 0, 0, 0);
                    accHi = __builtin_amdgcn_mfma_f32_16x16x32_f16(a, b1, accHi, 0, 0, 0);
                }

                // Epilogue: lane holds D[row=q*4+rr][col=m]; 16 lanes cover
                // 16 consecutive channels -> coalesced 64 B atomic segments.
                if (local) {
                    #pragma unroll
                    for (int rr = 0; rr < 4; ++rr) {
                        const long e2  = e0 + q * 4 + rr;
                        const int  dst = __builtin_nontemporal_load(edge_dst + e2);
                        float* orow = obase + (long)dst * NCOUT;
                        __hip_atomic_fetch_add(orow + m,      accLo[rr],
                            __ATOMIC_RELAXED, __HIP_MEMORY_SCOPE_WORKGROUP);
                        __hip_atomic_fetch_add(orow + m + 16, accHi[rr],
                            __ATOMIC_RELAXED, __HIP_MEMORY_SCOPE_WORKGROUP);
                    }
                } else {
                    #pragma unroll
                    for (int rr = 0; rr < 4; ++rr) {
                        const long e2  = e0 + q * 4 + rr;
                        const int  dst = __builtin_nontemporal_load(edge_dst + e2);
                        float* orow = obase + (long)dst * NCOUT;
                        atomicAdd(orow + m,      accLo[rr]);
                        atomicAdd(orow + m + 16, accHi[rr]);
                    }
                }
            }
        }
    }
}

// ---------------------------------------------------------------------------
// Fallback A (ws >= 2 MB): round-5 kernel verbatim (best measured: 248 us).
// ---------------------------------------------------------------------------
__global__ __launch_bounds__(256, 4)
void pconv_f16_kernel(const _Float16* __restrict__ feat16,
                      const float* __restrict__ edge_vec,
                      const float* __restrict__ W,
                      const float* __restrict__ mu,
                      const int* __restrict__ edge_src,
                      const int* __restrict__ edge_dst,
                      const int* __restrict__ n_norm_p,
                      float* __restrict__ out)
{
    __shared__ _Float16 wsw[16 * 2 * 64 * 8];
    __shared__ float mus[16];

    const int tid = threadIdx.x;
    for (int idx = tid; idx < 16384; idx += 256) {
        int j = idx & 7;
        int l = (idx >> 3) & 63;
        int u = (idx >> 9) & 1;
        int s = idx >> 10;
        int n = (l & 15) + (u << 4);
        int i = ((l >> 4) << 3) | j;
        wsw[idx] = (_Float16)W[(s * NCOUT + n) * NCIN + i];
    }
    if (tid < 16) mus[tid] = mu[tid];
    __syncthreads();

    const int lane = tid & 63;
    const int wv   = tid >> 6;
    const int m    = lane & 15;
    const int q    = lane >> 4;

    const int nn = n_norm_p[0];
    const float scale = (nn > 0) ? rsqrtf((float)nn) : 1.0f;

    const int g    = blockIdx.x & 7;
    const int bb   = g >> 1;
    const int sub  = g & 1;
    const int bi   = blockIdx.x >> 3;

    const _Float16* fbase = feat16 + ((long)bb << 13) * NCIN;
    float* obase = out + ((long)bb << 13) * NCOUT;
    const long ebatch = (long)bb * NE;

    for (int i = bi; i < TILES_PER_BATCH / 2; i += 128) {
        const int  tloc  = (i << 1) + sub;
        const long ebase = ebatch + (long)tloc * 64 + (long)wv * 16;
        const long ge    = ebase + m;
        const int  src   = __builtin_nontemporal_load(edge_src + ge);

        half8 xh = *(const half8*)(fbase + (long)src * NCIN + q * 8);

        const float* ev = edge_vec + ge * 3;
        float vx = __builtin_nontemporal_load(ev + 0);
        float vy = __builtin_nontemporal_load(ev + 1);
        float vz = __builtin_nontemporal_load(ev + 2);
        float r = sqrtf(vx * vx + vy * vy + vz * vz);

        float rbf[16];
        #pragma unroll
        for (int s = 0; s < 16; ++s) {
            float d = r - mus[s];
            rbf[s] = __expf(-GAMMA * d * d);
        }

        floatx4 accLo = {0.f, 0.f, 0.f, 0.f};
        floatx4 accHi = {0.f, 0.f, 0.f, 0.f};

        #pragma unroll
        for (int s = 0; s < 16; ++s) {
            const _Float16 rh = (_Float16)rbf[s];
            half8 a = xh * rh;
            half8 b0 = *(const half8*)(wsw + ((s * 2 + 0) * 64 + lane) * 8);
            half8 b1 = *(const half8*)(wsw + ((s * 2 + 1) * 64 + lane) * 8);
            accLo = __builtin_amdgcn_mfma_f32_16x16x32_f16(a, b0, accLo, 0, 0, 0);
            accHi = __builtin_amdgcn_mfma_f32_16x16x32_f16(a, b1, accHi, 0, 0, 0);
        }

        #pragma unroll
        for (int rr = 0; rr < 4; ++rr) {
            const long e2  = ebase + q * 4 + rr;
            const int  dst = __builtin_nontemporal_load(edge_dst + e2);
            float* orow = obase + (long)dst * NCOUT;
            atomicAdd(orow + m,      accLo[rr] * scale);
            atomicAdd(orow + m + 16, accHi[rr] * scale);
        }
    }
}

// ---------------------------------------------------------------------------
// Fallback B (no workspace): round-3 kernel (f32 gathers).
// ---------------------------------------------------------------------------
__global__ __launch_bounds__(256, 4)
void pconv_mfma_kernel(const float* __restrict__ features,
                       const float* __restrict__ edge_vec,
                       const float* __restrict__ W,
                       const float* __restrict__ mu,
                       const int* __restrict__ edge_src,
                       const int* __restrict__ edge_dst,
                       const int* __restrict__ n_norm_p,
                       float* __restrict__ out)
{
    __shared__ _Float16 wsw[16 * 2 * 64 * 8];
    __shared__ float mus[16];

    const int tid = threadIdx.x;
    for (int idx = tid; idx < 16384; idx += 256) {
        int j = idx & 7;
        int l = (idx >> 3) & 63;
        int u = (idx >> 9) & 1;
        int s = idx >> 10;
        int n = (l & 15) + (u << 4);
        int i = ((l >> 4) << 3) | j;
        wsw[idx] = (_Float16)W[(s * NCOUT + n) * NCIN + i];
    }
    if (tid < 16) mus[tid] = mu[tid];
    __syncthreads();

    const int lane = tid & 63;
    const int wv   = tid >> 6;
    const int m    = lane & 15;
    const int q    = lane >> 4;

    const int nn = n_norm_p[0];
    const float scale = (nn > 0) ? rsqrtf((float)nn) : 1.0f;

    const int g    = blockIdx.x & 7;
    const int bb   = g >> 1;
    const int sub  = g & 1;
    const int bi   = blockIdx.x >> 3;

    const float* fbase = features + ((long)bb << 13) * NCIN;
    float* obase = out + ((long)bb << 13) * NCOUT;
    const long ebatch = (long)bb * NE;

    for (int i = bi; i < TILES_PER_BATCH / 2; i += 128) {
        const int  tloc  = (i << 1) + sub;
        const long ebase = ebatch + (long)tloc * 64 + (long)wv * 16;
        const long ge    = ebase + m;
        const int  src   = edge_src[ge];

        const float* xrow = fbase + (long)src * NCIN + q * 8;
        floatx4 xa = *(const floatx4*)(xrow);
        floatx4 xb = *(const floatx4*)(xrow + 4);

        const float* ev = edge_vec + ge * 3;
        float vx = ev[0], vy = ev[1], vz = ev[2];
        float r = sqrtf(vx * vx + vy * vy + vz * vz);

        float rbf[16];
        #pragma unroll
        for (int s = 0; s < 16; ++s) {
            float d = r - mus[s];
            rbf[s] = __expf(-GAMMA * d * d);
        }

        floatx4 accLo = {0.f, 0.f, 0.f, 0.f};
        floatx4 accHi = {0.f, 0.f, 0.f, 0.f};

        #pragma unroll
        for (int s = 0; s < 16; ++s) {
            const float rb = rbf[s];
            half8 a;
            a[0] = (_Float16)(rb * xa[0]);
            a[1] = (_Float16)(rb * xa[1]);
            a[2] = (_Float16)(rb * xa[2]);
            a[3] = (_Float16)(rb * xa[3]);
            a[4] = (_Float16)(rb * xb[0]);
            a[5] = (_Float16)(rb * xb[1]);
            a[6] = (_Float16)(rb * xb[2]);
            a[7] = (_Float16)(rb * xb[3]);
            half8 b0 = *(const half8*)(wsw + ((s * 2 + 0) * 64 + lane) * 8);
            half8 b1 = *(const half8*)(wsw + ((s * 2 + 1) * 64 + lane) * 8);
            accLo = __builtin_amdgcn_mfma_f32_16x16x32_f16(a, b0, accLo, 0, 0, 0);
            accHi = __builtin_amdgcn_mfma_f32_16x16x32_f16(a, b1, accHi, 0, 0, 0);
        }

        #pragma unroll
        for (int rr = 0; rr < 4; ++rr) {
            const long e2  = ebase + q * 4 + rr;
            const int  dst = edge_dst[e2];
            float* orow = obase + (long)dst * NCOUT;
            atomicAdd(orow + m,      accLo[rr] * scale);
            atomicAdd(orow + m + 16, accHi[rr] * scale);
        }
    }
}

extern "C" void kernel_launch(void* const* d_in, const int* in_sizes, int n_in,
                              void* d_out, int out_size, void* d_ws, size_t ws_size,
                              hipStream_t stream) {
    const float* features = (const float*)d_in[0];
    const float* edge_vec = (const float*)d_in[1];
    const float* W        = (const float*)d_in[2];
    const float* mu       = (const float*)d_in[3];
    const int*   edge_src = (const int*)d_in[4];
    const int*   edge_dst = (const int*)d_in[5];
    const int*   n_norm   = (const int*)d_in[6];
    float* out = (float*)d_out;

    // ws layout: partial[8][1MB] | ovf[4MB] | f16[2MB] | qcnt[4KB]
    const size_t part_bytes = (size_t)NXCD * SLICE * sizeof(float);  //  8 MB
    const size_t ovf_bytes  = (size_t)NOUT * sizeof(float);          //  4 MB
    const size_t f16_bytes  = (size_t)NFEAT * sizeof(_Float16);      //  2 MB
    const size_t q_bytes    = 4096;
    const size_t need_full  = part_bytes + ovf_bytes + f16_bytes + q_bytes;

    if (d_ws != nullptr && ws_size >= need_full) {
        char* ws = (char*)d_ws;
        float*    partial = (float*)ws;
        float*    ovf     = (float*)(ws + part_bytes);
        _Float16* f16t    = (_Float16*)(ws + part_bytes + ovf_bytes);
        int*      qcnt    = (int*)(ws + part_bytes + ovf_bytes + f16_bytes);

        prep_kernel<<<1024, 256, 0, stream>>>(features, f16t,
                                              (floatx4*)partial, qcnt);
        pconv_queue_kernel<<<1024, 256, 0, stream>>>(f16t, edge_vec, W, mu,
                                                     edge_src, edge_dst,
                                                     partial, ovf, qcnt);
        reduce_kernel<<<1024, 256, 0, stream>>>((const floatx4*)partial,
                                                (const floatx4*)ovf,
                                                n_norm, (floatx4*)out);
    } else if (d_ws != nullptr && ws_size >= f16_bytes) {
        hipMemsetAsync(out, 0, (size_t)out_size * sizeof(float), stream);
        _Float16* f16t = (_Float16*)d_ws;
        cvt_f16_kernel<<<NFEAT / 8 / 256, 256, 0, stream>>>(features, f16t);
        pconv_f16_kernel<<<1024, 256, 0, stream>>>(f16t, edge_vec, W, mu,
                                                   edge_src, edge_dst, n_norm, out);
    } else {
        hipMemsetAsync(out, 0, (size_t)out_size * sizeof(float), stream);
        pconv_mfma_kernel<<<1024, 256, 0, stream>>>(features, edge_vec, W, mu,
                                                    edge_src, edge_dst, n_norm, out);
    }
}